// Round 6
// baseline (1512.539 us; speedup 1.0000x reference)
//
#include <hip/hip_runtime.h>
#include <stdint.h>

// ---------------- Threefry-2x32-20 (JAX-compatible) ----------------
#ifdef __HIP_DEVICE_COMPILE__
#define ROTL32(x, R) __builtin_amdgcn_alignbit((x), (x), 32u - (R))
#else
#define ROTL32(x, R) (((x) << (R)) | ((x) >> (32 - (R))))
#endif
#define TF_ROUND(x0, x1, R) { x0 += x1; x1 = ROTL32(x1, R); x1 ^= x0; }

__host__ __device__ __forceinline__ void tf2x32(uint32_t k0, uint32_t k1,
                                                uint32_t x0, uint32_t x1,
                                                uint32_t& o0, uint32_t& o1) {
  uint32_t k2 = k0 ^ k1 ^ 0x1BD11BDAu;
  x0 += k0; x1 += k1;
  TF_ROUND(x0, x1, 13) TF_ROUND(x0, x1, 15) TF_ROUND(x0, x1, 26) TF_ROUND(x0, x1, 6)
  x0 += k1; x1 += k2 + 1u;
  TF_ROUND(x0, x1, 17) TF_ROUND(x0, x1, 29) TF_ROUND(x0, x1, 16) TF_ROUND(x0, x1, 24)
  x0 += k2; x1 += k0 + 2u;
  TF_ROUND(x0, x1, 13) TF_ROUND(x0, x1, 15) TF_ROUND(x0, x1, 26) TF_ROUND(x0, x1, 6)
  x0 += k0; x1 += k1 + 3u;
  TF_ROUND(x0, x1, 17) TF_ROUND(x0, x1, 29) TF_ROUND(x0, x1, 16) TF_ROUND(x0, x1, 24)
  x0 += k1; x1 += k2 + 4u;
  TF_ROUND(x0, x1, 13) TF_ROUND(x0, x1, 15) TF_ROUND(x0, x1, 26) TF_ROUND(x0, x1, 6)
  x0 += k2; x1 += k0 + 5u;
  o0 = x0; o1 = x1;
}

struct KeySched { uint32_t k0[11]; uint32_t k1[11]; };  // [0]=init key, [1..10]=step keys

typedef __attribute__((ext_vector_type(8))) short  short8;
typedef __attribute__((ext_vector_type(4))) float  f32x4;

#define NSAMP 131072
#define DDIM  256
#define ROWS  32          // samples per block: 16 KB LDS -> 8 blocks/CU resident
#define MT    2           // 16-row MFMA tiles per wave (ROWS/16)

// partitionable 32-bit random_bits: counter i (hi=0), bits = o0 ^ o1
__device__ __forceinline__ uint32_t tf_bits(uint32_t k0, uint32_t k1, uint32_t ctr) {
  uint32_t o0, o1;
  tf2x32(k0, k1, 0u, ctr, o0, o1);
  return o0 ^ o1;
}

// Rare path (p ~ 2e-5 per element): staged f32 1/(1+exp(-x)) with
// correctly-rounded f32 exp via f64 — matches reference elementwise sigmoid.
__device__ __attribute__((noinline)) float sigmoid_exact(float x) {
  float e32 = (float)exp(-(double)x);   // correctly-rounded f32 exp
  return 1.0f / (1.0f + e32);           // IEEE f32 div (no fast-math)
}

__device__ __forceinline__ int zaddr(int row, int d) {
  // ROWS x 256 bf16, XOR-swizzled at 16B blocks for conflict-light ds_read_b128
  return row * 256 + ((((d >> 3) ^ (row & 7)) << 3)) + (d & 7);
}

__host__ __device__ __forceinline__ unsigned short f32_to_bf16_rne(float f) {
  uint32_t u; __builtin_memcpy(&u, &f, 4);
  u += 0x7FFFu + ((u >> 16) & 1u);
  return (unsigned short)(u >> 16);
}

// Pre-swizzle W into MFMA B-fragment order, split bf16 hi/lo (exact sum).
// frag index t = ((ntile*8 + kc)*64 + lane)*8 + j  ->  W[kc*32 + (lane>>4)*8 + j][ntile*16 + (lane&15)]
__global__ void prep_w(const float* __restrict__ W,
                       unsigned short* __restrict__ wh, unsigned short* __restrict__ wl) {
  int t = blockIdx.x * 256 + threadIdx.x;          // 0..65535
  int ntile = t >> 12, kc = (t >> 9) & 7, lane = (t >> 3) & 63, j = t & 7;
  int k   = kc * 32 + ((lane >> 4) << 3) + j;
  int col = ntile * 16 + (lane & 15);
  float wv = W[k * 256 + col];
  unsigned short hi = f32_to_bf16_rne(wv);
  float hif; { uint32_t hu = ((uint32_t)hi) << 16; __builtin_memcpy(&hif, &hu, 4); }
  wh[t] = hi;
  wl[t] = f32_to_bf16_rne(wv - hif);               // exact residual (Sterbenz)
}

// 32 samples x 256 cols per block. Wave w -> cols [64w, 64w+64).
// Per-wave acc tile 32x64 = 8 MFMA tiles = 32 f32 accum regs.
// __launch_bounds__(256,8): 8 blocks/CU (128 KB LDS, 29 KB slack — NOT the
// exact-160KB trap of round 4), 32 waves/CU nominal.
__global__ __launch_bounds__(256, 8)
void rbm_kernel(const float* __restrict__ h,
                const unsigned short* __restrict__ Wh,
                const unsigned short* __restrict__ Wl,
                float* __restrict__ out, KeySched ks) {
  __shared__ unsigned short Zs[ROWS * 256];   // 16 KB
  const int tid  = threadIdx.x;
  const int w    = tid >> 6;        // wave 0..3 -> cols [64w, 64w+64)
  const int lane = tid & 63;
  const int q    = lane >> 4;
  const int l15  = lane & 15;
  const int b    = blockIdx.x;
  const int cb   = w * 64;
  const int nbase = b * ROWS;

  float hreg[4];
  #pragma unroll
  for (int nt = 0; nt < 4; ++nt) hreg[nt] = h[cb + nt * 16 + l15];

  f32x4 acc[MT][4];
  #pragma unroll
  for (int mt = 0; mt < MT; ++mt)
    #pragma unroll
    for (int nt = 0; nt < 4; ++nt) acc[mt][nt] = (f32x4){0.f, 0.f, 0.f, 0.f};

  auto do_matmul = [&]() {   // acc = Z @ W (bf16 hi+lo, f32 accumulate)
    #pragma unroll
    for (int mt = 0; mt < MT; ++mt)
      #pragma unroll
      for (int nt = 0; nt < 4; ++nt) acc[mt][nt] = (f32x4){0.f, 0.f, 0.f, 0.f};
    #pragma unroll 2
    for (int kc = 0; kc < 8; ++kc) {
      short8 a[MT];
      #pragma unroll
      for (int mt = 0; mt < MT; ++mt) {
        int row = mt * 16 + l15;                       // A: m = lane&15
        int idx = row * 256 + ((((kc * 4 + q) ^ (row & 7)) << 3));  // k-chunk block
        a[mt] = *(const short8*)(Zs + idx);
      }
      #pragma unroll
      for (int nt = 0; nt < 4; ++nt) {
        int fidx = ((((4 * w + nt) * 8 + kc) * 64) + lane) * 8;
        short8 bh = *(const short8*)(Wh + fidx);
        short8 bl = *(const short8*)(Wl + fidx);
        #pragma unroll
        for (int mt = 0; mt < MT; ++mt)
          acc[mt][nt] = __builtin_amdgcn_mfma_f32_16x16x32_bf16(a[mt], bh, acc[mt][nt], 0, 0, 0);
        #pragma unroll
        for (int mt = 0; mt < MT; ++mt)
          acc[mt][nt] = __builtin_amdgcn_mfma_f32_16x16x32_bf16(a[mt], bl, acc[mt][nt], 0, 0, 0);
      }
    }
  };

  // s = -1: bernoulli init (x forced to 0 -> p = 0.5 exactly); s = 0..9: Gibbs
  // steps; s = 10: final matmul only (acc = z @ W for the energy).
  #pragma unroll 1
  for (int s = -1; s <= 10; ++s) {
    if (s >= 0) do_matmul();
    __syncthreads();
    if (s < 10) {
      const uint32_t kk0 = ks.k0[s + 1], kk1 = ks.k1[s + 1];
      const bool isInit = (s < 0);
      #pragma unroll
      for (int mt = 0; mt < MT; ++mt) {
        #pragma unroll
        for (int nt = 0; nt < 4; ++nt) {
          const int dcol = cb + nt * 16 + l15;
          const int rowb = mt * 16 + q * 4;            // C/D: row = quad*4 + reg
          const uint32_t cbase = (uint32_t)((nbase + rowb) * 256 + dcol);
          // 4 independent threefry chains in flight (hides the dep chain)
          uint32_t bits[4];
          #pragma unroll
          for (int r = 0; r < 4; ++r) bits[r] = tf_bits(kk0, kk1, cbase + 256u * (uint32_t)r);
          #pragma unroll
          for (int r = 0; r < 4; ++r) {
            float u = __uint_as_float((bits[r] >> 9) | 0x3f800000u) - 1.0f;
            float x = isInit ? 0.0f : (acc[mt][nt][r] + hreg[nt]);
            float x2 = x * x;
            float sg = fmaf(x, fmaf(x2, fmaf(x2, 2.0833333333333333e-03f,
                                                 -2.0833333333333332e-02f), 0.25f), 0.5f);
            if (__builtin_expect((fabsf(u - sg) <= 1e-5f) || (fabsf(x) >= 0.12f), 0))
              sg = sigmoid_exact(x);
            Zs[zaddr(rowb + r, dcol)] = (u < sg) ? (unsigned short)0x3F80u : (unsigned short)0u;
          }
          // cap register pressure: one 4-chain batch in flight at a time
          __builtin_amdgcn_sched_barrier(0);
        }
      }
    }
    __syncthreads();
  }

  // energy[n] = -(sum_d z*h + sum_d (z@W)*z); acc already holds y = z@W
  float rs[MT][4];
  #pragma unroll
  for (int mt = 0; mt < MT; ++mt) {
    #pragma unroll
    for (int r = 0; r < 4; ++r) {
      const int row = mt * 16 + q * 4 + r;
      float p = 0.f;
      #pragma unroll
      for (int nt = 0; nt < 4; ++nt) {
        const int dcol = cb + nt * 16 + l15;
        float z = (Zs[zaddr(row, dcol)] != 0) ? 1.0f : 0.0f;
        p += z * (hreg[nt] + acc[mt][nt][r]);
      }
      p += __shfl_xor(p, 1);
      p += __shfl_xor(p, 2);
      p += __shfl_xor(p, 4);
      p += __shfl_xor(p, 8);
      rs[mt][r] = p;   // 16-lane group sum (this wave's 64 cols)
    }
  }
  __syncthreads();                      // all Zs reads done -> reuse LDS as esum
  float* esum = (float*)Zs;             // esum[row*4 + w]
  #pragma unroll
  for (int mt = 0; mt < MT; ++mt)
    #pragma unroll
    for (int r = 0; r < 4; ++r)
      if (l15 == 0) esum[(mt * 16 + q * 4 + r) * 4 + w] = rs[mt][r];
  __syncthreads();
  if (tid < ROWS) {
    float e = esum[tid * 4 + 0] + esum[tid * 4 + 1] + esum[tid * 4 + 2] + esum[tid * 4 + 3];
    out[nbase + tid] = -e;
  }
}

extern "C" void kernel_launch(void* const* d_in, const int* in_sizes, int n_in,
                              void* d_out, int out_size, void* d_ws, size_t ws_size,
                              hipStream_t stream) {
  const float* h = (const float*)d_in[0];
  const float* W = (const float*)d_in[1];
  float* out = (float*)d_out;
  unsigned short* wh = (unsigned short*)d_ws;      // 65536 bf16 = 128 KB
  unsigned short* wl = wh + 65536;                 // +128 KB

  prep_w<<<256, 256, 0, stream>>>(W, wh, wl);

  // Host-side key schedule (jax_threefry_partitionable=True semantics):
  // root = key(42) = (0,42); split -> k_init = E(0,0), k_loop = E(0,1);
  // step_keys[s] = E_{k_loop}(0, s)
  KeySched ks;
  uint32_t i0, i1, l0, l1;
  tf2x32(0u, 42u, 0u, 0u, i0, i1);
  tf2x32(0u, 42u, 0u, 1u, l0, l1);
  ks.k0[0] = i0; ks.k1[0] = i1;
  for (uint32_t s = 0; s < 10; ++s) tf2x32(l0, l1, 0u, s, ks.k0[1 + s], ks.k1[1 + s]);

  rbm_kernel<<<NSAMP / ROWS, 256, 0, stream>>>(h, wh, wl, out, ks);
}

// Round 7
// 955.758 us; speedup vs baseline: 1.5826x; 1.5826x over previous
//
#include <hip/hip_runtime.h>
#include <stdint.h>

// ---------------- Threefry-2x32-20 (JAX-compatible) ----------------
#ifdef __HIP_DEVICE_COMPILE__
#define ROTL32(x, R) __builtin_amdgcn_alignbit((x), (x), 32u - (R))
#else
#define ROTL32(x, R) (((x) << (R)) | ((x) >> (32 - (R))))
#endif
#define TF_ROUND(x0, x1, R) { x0 += x1; x1 = ROTL32(x1, R); x1 ^= x0; }

__host__ __device__ __forceinline__ void tf2x32(uint32_t k0, uint32_t k1,
                                                uint32_t x0, uint32_t x1,
                                                uint32_t& o0, uint32_t& o1) {
  uint32_t k2 = k0 ^ k1 ^ 0x1BD11BDAu;
  x0 += k0; x1 += k1;
  TF_ROUND(x0, x1, 13) TF_ROUND(x0, x1, 15) TF_ROUND(x0, x1, 26) TF_ROUND(x0, x1, 6)
  x0 += k1; x1 += k2 + 1u;
  TF_ROUND(x0, x1, 17) TF_ROUND(x0, x1, 29) TF_ROUND(x0, x1, 16) TF_ROUND(x0, x1, 24)
  x0 += k2; x1 += k0 + 2u;
  TF_ROUND(x0, x1, 13) TF_ROUND(x0, x1, 15) TF_ROUND(x0, x1, 26) TF_ROUND(x0, x1, 6)
  x0 += k0; x1 += k1 + 3u;
  TF_ROUND(x0, x1, 17) TF_ROUND(x0, x1, 29) TF_ROUND(x0, x1, 16) TF_ROUND(x0, x1, 24)
  x0 += k1; x1 += k2 + 4u;
  TF_ROUND(x0, x1, 13) TF_ROUND(x0, x1, 15) TF_ROUND(x0, x1, 26) TF_ROUND(x0, x1, 6)
  x0 += k2; x1 += k0 + 5u;
  o0 = x0; o1 = x1;
}

struct KeySched { uint32_t k0[11]; uint32_t k1[11]; };  // [0]=init key, [1..10]=step keys

typedef __attribute__((ext_vector_type(8))) short  short8;
typedef __attribute__((ext_vector_type(4))) float  f32x4;

#define NSAMP 131072
#define DDIM  256
#define ROWS  32          // samples per block
#define MT    2           // 16-row MFMA tiles per wave (ROWS/16)

// partitionable 32-bit random_bits: counter i (hi=0), bits = o0 ^ o1
__device__ __forceinline__ uint32_t tf_bits(uint32_t k0, uint32_t k1, uint32_t ctr) {
  uint32_t o0, o1;
  tf2x32(k0, k1, 0u, ctr, o0, o1);
  return o0 ^ o1;
}

// Rare path (p ~ 2e-5 per element): staged f32 1/(1+exp(-x)) with
// correctly-rounded f32 exp via f64 — matches reference elementwise sigmoid.
__device__ __attribute__((noinline)) float sigmoid_exact(float x) {
  float e32 = (float)exp(-(double)x);   // correctly-rounded f32 exp
  return 1.0f / (1.0f + e32);           // IEEE f32 div (no fast-math)
}

__device__ __forceinline__ int zaddr(int row, int d) {
  // ROWS x 256 bf16, XOR-swizzled at 16B blocks for conflict-light ds_read_b128
  return row * 256 + ((((d >> 3) ^ (row & 7)) << 3)) + (d & 7);
}

__host__ __device__ __forceinline__ unsigned short f32_to_bf16_rne(float f) {
  uint32_t u; __builtin_memcpy(&u, &f, 4);
  u += 0x7FFFu + ((u >> 16) & 1u);
  return (unsigned short)(u >> 16);
}

// Pre-swizzle W into MFMA B-fragment order, split bf16 hi/lo (exact sum).
// frag index t = ((ntile*8 + kc)*64 + lane)*8 + j  ->  W[kc*32 + (lane>>4)*8 + j][ntile*16 + (lane&15)]
__global__ void prep_w(const float* __restrict__ W,
                       unsigned short* __restrict__ wh, unsigned short* __restrict__ wl) {
  int t = blockIdx.x * 256 + threadIdx.x;          // 0..65535
  int ntile = t >> 12, kc = (t >> 9) & 7, lane = (t >> 3) & 63, j = t & 7;
  int k   = kc * 32 + ((lane >> 4) << 3) + j;
  int col = ntile * 16 + (lane & 15);
  float wv = W[k * 256 + col];
  unsigned short hi = f32_to_bf16_rne(wv);
  float hif; { uint32_t hu = ((uint32_t)hi) << 16; __builtin_memcpy(&hif, &hu, 4); }
  wh[t] = hi;
  wl[t] = f32_to_bf16_rne(wv - hif);               // exact residual (Sterbenz)
}

// 32 samples x 256 cols per block, DOUBLE-BUFFERED Zs: matmul(s) reads
// Z[s&1] while sampling(s) writes Z[(s+1)&1] -> NO mid-step barrier, one
// __syncthreads per step. Waves free-run within a step: one wave's sampling
// VALU overlaps another's MFMA (phase-serialization fix; R6 showed VALUBusy
// pinned ~60% at any occupancy due to the matmul<->sample barrier lockstep).
// (256,4): 4 blocks/CU, VGPR budget 128 (R6's (256,8) squeezed VGPR to 32
// and killed threefry ILP; R4's (256,5) same trap).
__global__ __launch_bounds__(256, 4)
void rbm_kernel(const float* __restrict__ h,
                const unsigned short* __restrict__ Wh,
                const unsigned short* __restrict__ Wl,
                float* __restrict__ out, KeySched ks) {
  __shared__ unsigned short Zbuf[2][ROWS * 256];   // 2 x 16 KB
  const int tid  = threadIdx.x;
  const int w    = tid >> 6;        // wave 0..3 -> cols [64w, 64w+64)
  const int lane = tid & 63;
  const int q    = lane >> 4;
  const int l15  = lane & 15;
  const int b    = blockIdx.x;
  const int cb   = w * 64;
  const int nbase = b * ROWS;

  float hreg[4];
  #pragma unroll
  for (int nt = 0; nt < 4; ++nt) hreg[nt] = h[cb + nt * 16 + l15];

  f32x4 acc[MT][4];
  #pragma unroll
  for (int mt = 0; mt < MT; ++mt)
    #pragma unroll
    for (int nt = 0; nt < 4; ++nt) acc[mt][nt] = (f32x4){0.f, 0.f, 0.f, 0.f};

  auto do_matmul = [&](const unsigned short* Zin) {  // acc = Z @ W (bf16 hi+lo)
    #pragma unroll
    for (int mt = 0; mt < MT; ++mt)
      #pragma unroll
      for (int nt = 0; nt < 4; ++nt) acc[mt][nt] = (f32x4){0.f, 0.f, 0.f, 0.f};
    #pragma unroll 2
    for (int kc = 0; kc < 8; ++kc) {
      short8 a[MT];
      #pragma unroll
      for (int mt = 0; mt < MT; ++mt) {
        int row = mt * 16 + l15;                       // A: m = lane&15
        int idx = row * 256 + ((((kc * 4 + q) ^ (row & 7)) << 3));  // k-chunk block
        a[mt] = *(const short8*)(Zin + idx);
      }
      #pragma unroll
      for (int nt = 0; nt < 4; ++nt) {
        int fidx = ((((4 * w + nt) * 8 + kc) * 64) + lane) * 8;
        short8 bh = *(const short8*)(Wh + fidx);
        short8 bl = *(const short8*)(Wl + fidx);
        #pragma unroll
        for (int mt = 0; mt < MT; ++mt)
          acc[mt][nt] = __builtin_amdgcn_mfma_f32_16x16x32_bf16(a[mt], bh, acc[mt][nt], 0, 0, 0);
        #pragma unroll
        for (int mt = 0; mt < MT; ++mt)
          acc[mt][nt] = __builtin_amdgcn_mfma_f32_16x16x32_bf16(a[mt], bl, acc[mt][nt], 0, 0, 0);
      }
    }
  };

  // s = -1: bernoulli init (x = 0 -> p = 0.5 exactly) writes Z[0];
  // s = 0..9: matmul reads Z[s&1], sampling writes Z[(s+1)&1];
  // s = 10: final matmul only (reads Z[0] = final z) for the energy.
  #pragma unroll 1
  for (int s = -1; s <= 10; ++s) {
    if (s >= 0) do_matmul(Zbuf[s & 1]);
    if (s < 10) {
      unsigned short* Zout = Zbuf[(s + 1) & 1];
      const uint32_t kk0 = ks.k0[s + 1], kk1 = ks.k1[s + 1];
      const bool isInit = (s < 0);
      #pragma unroll
      for (int mt = 0; mt < MT; ++mt) {
        #pragma unroll
        for (int nt = 0; nt < 4; ++nt) {
          const int dcol = cb + nt * 16 + l15;
          const int rowb = mt * 16 + q * 4;            // C/D: row = quad*4 + reg
          const uint32_t cbase = (uint32_t)((nbase + rowb) * 256 + dcol);
          // 4 independent threefry chains in flight (hides the dep chain)
          uint32_t bits[4];
          #pragma unroll
          for (int r = 0; r < 4; ++r) bits[r] = tf_bits(kk0, kk1, cbase + 256u * (uint32_t)r);
          #pragma unroll
          for (int r = 0; r < 4; ++r) {
            float u = __uint_as_float((bits[r] >> 9) | 0x3f800000u) - 1.0f;
            float x = isInit ? 0.0f : (acc[mt][nt][r] + hreg[nt]);
            float x2 = x * x;
            float sg = fmaf(x, fmaf(x2, fmaf(x2, 2.0833333333333333e-03f,
                                                 -2.0833333333333332e-02f), 0.25f), 0.5f);
            if (__builtin_expect((fabsf(u - sg) <= 1e-5f) || (fabsf(x) >= 0.12f), 0))
              sg = sigmoid_exact(x);
            Zout[zaddr(rowb + r, dcol)] = (u < sg) ? (unsigned short)0x3F80u : (unsigned short)0u;
          }
          // cap register pressure: one 4-chain batch in flight at a time
          __builtin_amdgcn_sched_barrier(0);
        }
      }
    }
    __syncthreads();   // sampling(s) writes visible before matmul(s+1) reads
  }

  // energy[n] = -(sum_d z*h + sum_d (z@W)*z); acc holds y = z@W, z in Zbuf[0]
  const unsigned short* Zfin = Zbuf[0];
  float rs[MT][4];
  #pragma unroll
  for (int mt = 0; mt < MT; ++mt) {
    #pragma unroll
    for (int r = 0; r < 4; ++r) {
      const int row = mt * 16 + q * 4 + r;
      float p = 0.f;
      #pragma unroll
      for (int nt = 0; nt < 4; ++nt) {
        const int dcol = cb + nt * 16 + l15;
        float z = (Zfin[zaddr(row, dcol)] != 0) ? 1.0f : 0.0f;
        p += z * (hreg[nt] + acc[mt][nt][r]);
      }
      p += __shfl_xor(p, 1);
      p += __shfl_xor(p, 2);
      p += __shfl_xor(p, 4);
      p += __shfl_xor(p, 8);
      rs[mt][r] = p;   // 16-lane group sum (this wave's 64 cols)
    }
  }
  __syncthreads();                      // Zbuf[1] reads long done -> reuse as esum
  float* esum = (float*)Zbuf[1];        // esum[row*4 + w]
  #pragma unroll
  for (int mt = 0; mt < MT; ++mt)
    #pragma unroll
    for (int r = 0; r < 4; ++r)
      if (l15 == 0) esum[(mt * 16 + q * 4 + r) * 4 + w] = rs[mt][r];
  __syncthreads();
  if (tid < ROWS) {
    float e = esum[tid * 4 + 0] + esum[tid * 4 + 1] + esum[tid * 4 + 2] + esum[tid * 4 + 3];
    out[nbase + tid] = -e;
  }
}

extern "C" void kernel_launch(void* const* d_in, const int* in_sizes, int n_in,
                              void* d_out, int out_size, void* d_ws, size_t ws_size,
                              hipStream_t stream) {
  const float* h = (const float*)d_in[0];
  const float* W = (const float*)d_in[1];
  float* out = (float*)d_out;
  unsigned short* wh = (unsigned short*)d_ws;      // 65536 bf16 = 128 KB
  unsigned short* wl = wh + 65536;                 // +128 KB

  prep_w<<<256, 256, 0, stream>>>(W, wh, wl);

  // Host-side key schedule (jax_threefry_partitionable=True semantics):
  // root = key(42) = (0,42); split -> k_init = E(0,0), k_loop = E(0,1);
  // step_keys[s] = E_{k_loop}(0, s)
  KeySched ks;
  uint32_t i0, i1, l0, l1;
  tf2x32(0u, 42u, 0u, 0u, i0, i1);
  tf2x32(0u, 42u, 0u, 1u, l0, l1);
  ks.k0[0] = i0; ks.k1[0] = i1;
  for (uint32_t s = 0; s < 10; ++s) tf2x32(l0, l1, 0u, s, ks.k0[1 + s], ks.k1[1 + s]);

  rbm_kernel<<<NSAMP / ROWS, 256, 0, stream>>>(h, wh, wl, out, ks);
}